// Round 1
// baseline (501.168 us; speedup 1.0000x reference)
//
#include <hip/hip_runtime.h>
#include <cstdint>

#define B_ 2
#define E_ 16
#define H_ 160
#define W_ 288
#define N_ 12
#define T_ 2
#define HW_ (H_*W_)        // 46080
#define P_ (T_*HW_)        // 92160
#define NPAD_ 131072       // 2^17
#define NINST (B_*N_)      // 24
#define CHUNK 8192         // 64 KiB of u64 in LDS

typedef unsigned long long u64;
typedef unsigned int u32;

__device__ inline float waveReduceSum(float v){
  #pragma unroll
  for(int o=32;o>0;o>>=1) v += __shfl_down(v, o, 64);
  return v;
}

// ---------------- Pass A: masked sums (mean numerator) + count ----------------
__global__ void k_sums(const float* __restrict__ mf1, const float* __restrict__ mf2,
                       const int* __restrict__ gt,
                       float* __restrict__ sumEmb, float* __restrict__ cnt){
  int bn = blockIdx.x;               // 0..23
  int b  = bn / N_;
  int base = blockIdx.y * 1024;      // 90 chunks of 1024 px, 1024 | HW_
  int t = base / HW_;
  int rbase = base - t*HW_;
  const float* ep = (t ? mf2 : mf1) + (size_t)b*E_*HW_;
  const int*   gp = gt + ((size_t)bn*T_ + t)*HW_;

  float acc[E_]; float c = 0.f;
  #pragma unroll
  for(int e=0;e<E_;e++) acc[e]=0.f;
  #pragma unroll
  for(int k=0;k<4;k++){
    int r = rbase + k*256 + threadIdx.x;
    float m = (float)gp[r];
    c += m;
    #pragma unroll
    for(int e=0;e<E_;e++) acc[e] = fmaf(m, ep[(size_t)e*HW_ + r], acc[e]);
  }
  __shared__ float red[E_+1];
  if(threadIdx.x < E_+1) red[threadIdx.x] = 0.f;
  __syncthreads();
  int lane = threadIdx.x & 63;
  #pragma unroll
  for(int e=0;e<E_;e++){
    float r = waveReduceSum(acc[e]);
    if(lane==0) atomicAdd(&red[e], r);
  }
  { float r = waveReduceSum(c); if(lane==0) atomicAdd(&red[E_], r); }
  __syncthreads();
  if(threadIdx.x < E_) atomicAdd(&sumEmb[bn*E_ + threadIdx.x], red[threadIdx.x]);
  if(threadIdx.x == E_) atomicAdd(&cnt[bn], red[E_]);
}

__global__ void k_fin_mean(const float* __restrict__ sumEmb, const float* __restrict__ cnt,
                           float* __restrict__ mean){
  int i = threadIdx.x;  // 384
  mean[i] = sumEmb[i] / cnt[i>>4];
}

// ---------------- Pass B: masked sum of (emb-mean)^2 -> variance ----------------
__global__ void k_var(const float* __restrict__ mf1, const float* __restrict__ mf2,
                      const int* __restrict__ gt, const float* __restrict__ mean,
                      float* __restrict__ sumD2){
  int bn = blockIdx.x;
  int b  = bn / N_;
  int base = blockIdx.y * 1024;
  int t = base / HW_;
  int rbase = base - t*HW_;
  const float* ep = (t ? mf2 : mf1) + (size_t)b*E_*HW_;
  const int*   gp = gt + ((size_t)bn*T_ + t)*HW_;

  float mn[E_];
  #pragma unroll
  for(int e=0;e<E_;e++) mn[e] = mean[bn*E_ + e];

  float acc[E_];
  #pragma unroll
  for(int e=0;e<E_;e++) acc[e]=0.f;
  #pragma unroll
  for(int k=0;k<4;k++){
    int r = rbase + k*256 + threadIdx.x;
    float m = (float)gp[r];
    #pragma unroll
    for(int e=0;e<E_;e++){
      float d = ep[(size_t)e*HW_ + r] - mn[e];
      acc[e] = fmaf(m*d, d, acc[e]);
    }
  }
  __shared__ float red[E_];
  if(threadIdx.x < E_) red[threadIdx.x] = 0.f;
  __syncthreads();
  int lane = threadIdx.x & 63;
  #pragma unroll
  for(int e=0;e<E_;e++){
    float r = waveReduceSum(acc[e]);
    if(lane==0) atomicAdd(&red[e], r);
  }
  __syncthreads();
  if(threadIdx.x < E_) atomicAdd(&sumD2[bn*E_ + threadIdx.x], red[threadIdx.x]);
}

__global__ void k_fin_var(const float* __restrict__ sumD2, const float* __restrict__ cnt,
                          float* __restrict__ var){
  int i = threadIdx.x;  // 384
  var[i] = sumD2[i] / (cnt[i>>4] - 1.0f);
}

// ---------------- Pass C: errors -> packed sort keys ----------------
// key = (f32_bits(err) << 32) | ~p ; err >= 0 so bits are order-monotonic.
// Descending u64 sort == descending err, ties broken by ascending p (stable argsort).
__global__ void k_keys(const float* __restrict__ mf1, const float* __restrict__ mf2,
                       const int* __restrict__ gt, const float* __restrict__ mean,
                       const float* __restrict__ var, u64* __restrict__ keys){
  __shared__ float sm[N_*E_], sv[N_*E_];
  int b = blockIdx.x;
  for(int i=threadIdx.x; i<N_*E_; i+=256){
    sm[i] = mean[b*N_*E_ + i];
    sv[i] = var [b*N_*E_ + i];
  }
  __syncthreads();
  int p = blockIdx.y*256 + threadIdx.x;   // 0..NPAD_-1 ; chunks align with HW_
  if(p < P_){
    int t = p / HW_;
    int r = p - t*HW_;
    const float* ep = (t ? mf2 : mf1) + (size_t)b*E_*HW_;
    float v[E_];
    #pragma unroll
    for(int e=0;e<E_;e++) v[e] = ep[(size_t)e*HW_ + r];
    #pragma unroll
    for(int n=0;n<N_;n++){
      float d = 0.f;
      #pragma unroll
      for(int e=0;e<E_;e++){
        float df = v[e] - sm[n*E_+e];
        d = fmaf(df*df, sv[n*E_+e], d);
      }
      float logits = 2.f*__expf(-0.5f*d) - 1.f;
      float m = (float)gt[(((size_t)(b*N_+n))*T_ + t)*HW_ + r];
      float sign = 2.f*m - 1.f;
      float err = 1.f - logits*sign;       // >= 0
      u64 key = ((u64)__float_as_uint(err) << 32) | (u32)(~(u32)p);
      keys[(size_t)(b*N_+n)*NPAD_ + p] = key;
    }
  } else {
    #pragma unroll
    for(int n=0;n<N_;n++)
      keys[(size_t)(b*N_+n)*NPAD_ + p] = 0ull;   // pads sort strictly last
  }
}

// ---------------- Pass D: per-instance bitonic sort (descending) ----------------
// direction: descending iff (global_elem_index & k) == 0  -> final pass fully descending.
__global__ __launch_bounds__(1024) void k_sort_local_full(u64* __restrict__ keys){
  __shared__ u64 s[CHUNK];
  int inst = blockIdx.x, ch = blockIdx.y;
  u64* g = keys + (size_t)inst*NPAD_ + (size_t)ch*CHUNK;
  int gbase = ch*CHUNK;
  for(int i=threadIdx.x; i<CHUNK; i+=1024) s[i]=g[i];
  __syncthreads();
  for(int k=2; k<=CHUNK; k<<=1){
    for(int j=k>>1; j>0; j>>=1){
      for(int t=threadIdx.x; t<CHUNK/2; t+=1024){
        int i = ((t & ~(j-1))<<1) | (t & (j-1));
        int l = i | j;
        bool desc = (((gbase + i) & k) == 0);
        u64 a = s[i], b = s[l];
        bool sw = desc ? (a < b) : (a > b);
        if(sw){ s[i]=b; s[l]=a; }
      }
      __syncthreads();
    }
  }
  for(int i=threadIdx.x; i<CHUNK; i+=1024) g[i]=s[i];
}

__global__ void k_sort_global(u64* __restrict__ keys, int k, int j){
  int inst = blockIdx.y;
  int t = blockIdx.x*256 + threadIdx.x;     // 0..NPAD_/2-1
  u64* g = keys + (size_t)inst*NPAD_;
  int i = ((t & ~(j-1))<<1) | (t & (j-1));
  int l = i | j;
  bool desc = ((i & k) == 0);
  u64 a = g[i], b = g[l];
  bool sw = desc ? (a < b) : (a > b);
  if(sw){ g[i]=b; g[l]=a; }
}

__global__ __launch_bounds__(1024) void k_sort_local_merge(u64* __restrict__ keys, int k){
  __shared__ u64 s[CHUNK];
  int inst = blockIdx.x, ch = blockIdx.y;
  u64* g = keys + (size_t)inst*NPAD_ + (size_t)ch*CHUNK;
  int gbase = ch*CHUNK;
  for(int i=threadIdx.x; i<CHUNK; i+=1024) s[i]=g[i];
  __syncthreads();
  for(int j=CHUNK>>1; j>0; j>>=1){
    for(int t=threadIdx.x; t<CHUNK/2; t+=1024){
      int i = ((t & ~(j-1))<<1) | (t & (j-1));
      int l = i | j;
      bool desc = (((gbase + i) & k) == 0);
      u64 a = s[i], b = s[l];
      bool sw = desc ? (a < b) : (a > b);
      if(sw){ s[i]=b; s[l]=a; }
    }
    __syncthreads();
  }
  for(int i=threadIdx.x; i<CHUNK; i+=1024) g[i]=s[i];
}

// ---------------- Pass E: chunked scan + lovasz dot ----------------
__global__ __launch_bounds__(1024) void k_loss(const u64* __restrict__ keys,
                                               const int* __restrict__ gt,
                                               const float* __restrict__ cnt,
                                               float* __restrict__ out){
  const int VPT = 4, PER_ITER = 4096;
  int bn = blockIdx.x;
  const u64* g  = keys + (size_t)bn*NPAD_;
  const int* gi = gt + (size_t)bn*P_;
  float G = cnt[bn];
  __shared__ float wsum[16];
  __shared__ float carry;
  __shared__ float rs[16];
  if(threadIdx.x==0) carry = 0.f;
  __syncthreads();
  int lane = threadIdx.x & 63, wave = threadIdx.x >> 6;
  float lsum = 0.f;
  int iters = (P_ + PER_ITER - 1)/PER_ITER;   // 23
  for(int it=0; it<iters; ++it){
    int base = it*PER_ITER + threadIdx.x*VPT;
    float l[VPT], e[VPT];
    #pragma unroll
    for(int k=0;k<VPT;k++){
      int pos = base + k;
      if(pos < P_){
        u64 key = g[pos];
        u32 idx = ~(u32)key;
        e[k] = fmaxf(__uint_as_float((u32)(key>>32)), 0.f);
        l[k] = (float)gi[idx];
      } else { e[k]=0.f; l[k]=0.f; }
    }
    float tl = l[0]+l[1]+l[2]+l[3];
    // wave-inclusive scan of per-thread totals
    float sc = tl;
    #pragma unroll
    for(int o=1;o<64;o<<=1){ float v = __shfl_up(sc, o, 64); if(lane>=o) sc += v; }
    if(lane==63) wsum[wave] = sc;
    __syncthreads();
    if(threadIdx.x==0){
      float run = carry;
      #pragma unroll
      for(int wv=0; wv<16; wv++){ float tmp = wsum[wv]; wsum[wv] = run; run += tmp; }
      carry = run;
    }
    __syncthreads();
    float c = wsum[wave] + (sc - tl);   // exclusive prefix for this thread
    #pragma unroll
    for(int k=0;k<VPT;k++){
      int pos = base + k;
      c += l[k];
      if(pos < P_){
        float fi = (float)pos;
        float jc = 1.f - (G - c)/(G + (fi+1.f) - c);
        float grad;
        if(pos == 0) grad = jc;
        else {
          float cp = c - l[k];
          float jp = 1.f - (G - cp)/(G + fi - cp);
          grad = jc - jp;
        }
        lsum += e[k]*grad;
      }
    }
    __syncthreads();   // protect wsum/carry before next iteration
  }
  float tot = waveReduceSum(lsum);
  if(lane==0) rs[wave] = tot;
  __syncthreads();
  if(threadIdx.x==0){
    float s = 0.f;
    #pragma unroll
    for(int wv=0; wv<16; wv++) s += rs[wv];
    atomicAdd(out, s * (1.0f/(float)NINST));
  }
}

extern "C" void kernel_launch(void* const* d_in, const int* in_sizes, int n_in,
                              void* d_out, int out_size, void* d_ws, size_t ws_size,
                              hipStream_t stream){
  const float* mf1 = (const float*)d_in[0];
  const float* mf2 = (const float*)d_in[1];
  const int*   gt  = (const int*)d_in[2];
  float* out = (float*)d_out;

  float* sumEmb = (float*)d_ws;      // 384
  float* cnt    = sumEmb + 384;      // 24
  float* mean   = cnt + 24;          // 384
  float* sumD2  = mean + 384;        // 384
  float* var    = sumD2 + 384;       // 384
  u64*   keys   = (u64*)((char*)d_ws + 8192);  // 24 * 131072 * 8 B = 25.2 MB

  hipMemsetAsync(d_ws, 0, 8192, stream);
  hipMemsetAsync(d_out, 0, sizeof(float), stream);

  k_sums<<<dim3(NINST, P_/1024), 256, 0, stream>>>(mf1, mf2, gt, sumEmb, cnt);
  k_fin_mean<<<1, 384, 0, stream>>>(sumEmb, cnt, mean);
  k_var<<<dim3(NINST, P_/1024), 256, 0, stream>>>(mf1, mf2, gt, mean, sumD2);
  k_fin_var<<<1, 384, 0, stream>>>(sumD2, cnt, var);
  k_keys<<<dim3(B_, NPAD_/256), 256, 0, stream>>>(mf1, mf2, gt, mean, var, keys);

  k_sort_local_full<<<dim3(NINST, NPAD_/CHUNK), 1024, 0, stream>>>(keys);
  for(int k = CHUNK*2; k <= NPAD_; k <<= 1){
    for(int j = k>>1; j >= CHUNK; j >>= 1)
      k_sort_global<<<dim3(NPAD_/2/256, NINST), 256, 0, stream>>>(keys, k, j);
    k_sort_local_merge<<<dim3(NINST, NPAD_/CHUNK), 1024, 0, stream>>>(keys, k);
  }

  k_loss<<<NINST, 1024, 0, stream>>>(keys, gt, cnt, out);
}